// Round 1
// baseline (685.836 us; speedup 1.0000x reference)
//
#include <hip/hip_runtime.h>

// FireLSTM: x[8192,512,4] fp32 -> LSTM(H=64) -> FC(64->1), out[8192] fp32.
//
// Strategy: batch is the only parallel dim (T=512 is a serial recurrence).
// 512 blocks x 256 thr (4 waves). Block owns 16 batch elems. Waves split the
// 4*H=256 gates by gate type (i,f,g,o). Per step each wave runs 12x
// mfma_f32_16x16x32_f16 with M=16 (batch), N=64 (its gates), K=96 = [h(64)|x(4)|pad].
// W^T fragments live in registers (loaded once). h lives in a 2KB XOR-swizzled
// LDS buffer (fp16). Gates exchanged via LDS in fp32 (activated by owning wave).
// c state: fp32 registers (4/thread). fp16 MFMA inputs for precision headroom.

typedef float f32x4 __attribute__((ext_vector_type(4)));
typedef _Float16 f16x8 __attribute__((ext_vector_type(8)));

#define TSEQ 512
#define IDIM 4
#define BPB 16          // batch per block
#define GSTRIDE 68      // gate LDS hidden-stride pad: (4*68)%32==16 -> 2-way (free)

__device__ __forceinline__ float fast_sigmoid(float v) {
    // rcp(1+exp(-v)); exp overflow -> inf -> rcp -> 0 (graceful)
    return __builtin_amdgcn_rcpf(1.0f + __expf(-v));
}
__device__ __forceinline__ float fast_tanh(float v) {
    return 2.0f * __builtin_amdgcn_rcpf(1.0f + __expf(-2.0f * v)) - 1.0f;
}

__global__ __launch_bounds__(256, 2) void lstm_fused(
    const float* __restrict__ x,
    const float* __restrict__ W_ih,
    const float* __restrict__ W_hh,
    const float* __restrict__ b_ih,
    const float* __restrict__ b_hh,
    const float* __restrict__ W_fc,
    const float* __restrict__ b_fc,
    float* __restrict__ out)
{
    __shared__ float gates[4 * BPB * GSTRIDE];                 // 17408 B, fp32
    __shared__ __align__(16) _Float16 hbuf[BPB * 64];          // 2048 B, swizzled

    const int tid  = threadIdx.x;
    const int lane = tid & 63;
    const int wv   = tid >> 6;       // wave id == gate type (0=i,1=f,2=g,3=o)
    const int b0   = blockIdx.x * BPB;
    const int r    = lane & 15;      // A-row / C-col index
    const int g16  = lane >> 4;      // lane group (k-block)

    // ---- B-fragments: W^T slice for this wave's 64 gates, in registers ----
    // B[k][n]: lane col = lane&15, k = ks*32 + 8*(lane>>4) + j  (self-consistent
    // with A-frag k mapping below; any k-permutation cancels between A and B).
    f16x8 bfrag[4][3];
    float bias[4];
    #pragma unroll
    for (int nt = 0; nt < 4; ++nt) {
        const int g = wv * 64 + nt * 16 + r;   // global gate row
        #pragma unroll
        for (int ks = 0; ks < 2; ++ks) {       // k 0..63: W_hh
            const float* p = W_hh + g * 64 + ks * 32 + g16 * 8;
            f16x8 f;
            #pragma unroll
            for (int j = 0; j < 8; ++j) f[j] = (_Float16)p[j];
            bfrag[nt][ks] = f;
        }
        f16x8 f;                               // k 64..95: W_ih (4 rows) + zero pad
        #pragma unroll
        for (int j = 0; j < 8; ++j) f[j] = (_Float16)0.0f;
        if (g16 == 0) {
            #pragma unroll
            for (int j = 0; j < 4; ++j) f[j] = (_Float16)W_ih[g * IDIM + j];
        }
        bfrag[nt][2] = f;
        bias[nt] = b_ih[g] + b_hh[g];
    }
    const float wfc = W_fc[lane];   // lane == hidden idx for the FC epilogue
    const float bfc = b_fc[0];

    // ---- init state ----
    float c_reg[4] = {0.f, 0.f, 0.f, 0.f};
    float hsave[4] = {0.f, 0.f, 0.f, 0.f};
    for (int i = tid; i < BPB * 64; i += 256) hbuf[i] = (_Float16)0.0f;

    // x prefetch (lanes in group 0 carry the 16 batch rows)
    const float* xrow = x + (size_t)(b0 + r) * (TSEQ * IDIM);
    float4 xraw = make_float4(0.f, 0.f, 0.f, 0.f);
    if (g16 == 0) xraw = *(const float4*)(xrow);

    for (int t = 0; t < TSEQ; ++t) {
        // A-frag for k 64..95: x in lanes g16==0 elems 0..3, zero elsewhere
        f16x8 ax;
        ax[0] = (_Float16)xraw.x; ax[1] = (_Float16)xraw.y;
        ax[2] = (_Float16)xraw.z; ax[3] = (_Float16)xraw.w;
        ax[4] = (_Float16)0.0f; ax[5] = (_Float16)0.0f;
        ax[6] = (_Float16)0.0f; ax[7] = (_Float16)0.0f;

        // issue next-step x load early; consumed after 2 barriers -> latency hidden
        float4 xn = make_float4(0.f, 0.f, 0.f, 0.f);
        if (g16 == 0 && t + 1 < TSEQ) xn = *(const float4*)(xrow + (t + 1) * IDIM);

        __syncthreads();   // barrier 1: hbuf (h_{t-1}) ready; gates free to overwrite

        // A-frags (h) from swizzled hbuf: row r, chunk g16+4*ks, chunk^= r&7
        f16x8 a0, a1;
        {
            const char* hb = (const char*)hbuf;
            const int swz  = (r & 7) << 4;
            const int base = r * 128;
            a0 = *(const f16x8*)(hb + base + ((((g16 + 0) << 4)) ^ swz));
            a1 = *(const f16x8*)(hb + base + ((((g16 + 4) << 4)) ^ swz));
        }

        f32x4 acc[4];
        #pragma unroll
        for (int nt = 0; nt < 4; ++nt) {
            f32x4 a; a[0] = a[1] = a[2] = a[3] = bias[nt];
            a = __builtin_amdgcn_mfma_f32_16x16x32_f16(a0, bfrag[nt][0], a, 0, 0, 0);
            a = __builtin_amdgcn_mfma_f32_16x16x32_f16(a1, bfrag[nt][1], a, 0, 0, 0);
            a = __builtin_amdgcn_mfma_f32_16x16x32_f16(ax, bfrag[nt][2], a, 0, 0, 0);
            acc[nt] = a;
        }

        // activate (owning wave) + publish gates. C layout: col=lane&15, row=4*g16+reg
        #pragma unroll
        for (int nt = 0; nt < 4; ++nt) {
            #pragma unroll
            for (int reg = 0; reg < 4; ++reg) {
                float v = acc[nt][reg];
                float a = (wv == 2) ? fast_tanh(v) : fast_sigmoid(v);
                int brow = 4 * g16 + reg;
                gates[(wv * BPB + brow) * GSTRIDE + nt * 16 + r] = a;
            }
        }
        __syncthreads();   // barrier 2: all 4 gate types ready

        // state update: thread owns 4 (batch,hidden) pairs p = q*256+tid
        #pragma unroll
        for (int q = 0; q < 4; ++q) {
            int p  = q * 256 + tid;
            int bl = p >> 6;      // = q*4 + wv
            int hh = p & 63;      // = lane
            float gi = gates[(0 * BPB + bl) * GSTRIDE + hh];
            float gf = gates[(1 * BPB + bl) * GSTRIDE + hh];
            float gg = gates[(2 * BPB + bl) * GSTRIDE + hh];
            float go = gates[(3 * BPB + bl) * GSTRIDE + hh];
            float c  = gf * c_reg[q] + gi * gg;
            c_reg[q] = c;
            float hv = go * fast_tanh(c);
            hsave[q] = hv;
            // swizzled fp16 store: byte = bl*128 + hh*2, chunk ^= bl&7
            int byte = bl * 128 + hh * 2;
            byte ^= (bl & 7) << 4;
            *(_Float16*)((char*)hbuf + byte) = (_Float16)hv;
        }
        xraw = xn;
    }

    // ---- FC epilogue: out[b] = sum_h h[b][h]*W_fc[h] + b_fc ----
    // For pair q: all 64 lanes of wave wv share batch row q*4+wv, hh==lane.
    #pragma unroll
    for (int q = 0; q < 4; ++q) {
        float partial = hsave[q] * wfc;
        #pragma unroll
        for (int off = 32; off > 0; off >>= 1)
            partial += __shfl_down(partial, off);
        if (lane == 0) out[b0 + q * 4 + wv] = partial + bfc;
    }
}

extern "C" void kernel_launch(void* const* d_in, const int* in_sizes, int n_in,
                              void* d_out, int out_size, void* d_ws, size_t ws_size,
                              hipStream_t stream) {
    const float* x    = (const float*)d_in[0];
    const float* W_ih = (const float*)d_in[1];
    const float* W_hh = (const float*)d_in[2];
    const float* b_ih = (const float*)d_in[3];
    const float* b_hh = (const float*)d_in[4];
    const float* W_fc = (const float*)d_in[5];
    const float* b_fc = (const float*)d_in[6];
    float* out = (float*)d_out;

    const int B = in_sizes[0] / (TSEQ * IDIM);   // 8192
    lstm_fused<<<B / BPB, 256, 0, stream>>>(x, W_ih, W_hh, b_ih, b_hh, W_fc, b_fc, out);
}

// Round 3
// 440.374 us; speedup vs baseline: 1.5574x; 1.5574x over previous
//
#include <hip/hip_runtime.h>

// FireLSTM: x[8192,512,4] fp32 -> LSTM(H=64) -> FC(64->1), out[8192] fp32.
//
// 512 blocks x 256 thr (4 waves), block owns 16 batch rows. Per step:
//  phase A: wave wv computes RAW gates of type wv for all 16 batches via
//           12x mfma_f32_16x16x32_f16 (K=96 = h|x|pad), weights in registers
//           (pre-scaled by log2e, 2*log2e for g-gate). D layout (HW-verified):
//           row = 4*g16+reg = BATCH, col = r = gate. Store to LDS layout
//           [type][h=64 rows, stride 20 dwords][batch=16 cols] -> per tile nt
//           one ds_write_b128 at row nt*16+r, cols 4*g16..4*g16+3.
//  phase B: thread (wv,lane) owns cells (batch=4wv+q, h=lane): 4x ds_read_b128
//           (type t at row lane, cols 4wv..4wv+3), COMBINED activations
//           (8 trans/cell: 5 exp2 + 3 rcp), c in regs, h stored fp16 swizzled.
// x staged through LDS in 32-step chunks: the global load drains at one
// barrier per 32 steps instead of every step (syncthreads drains vmcnt).

typedef float f32x4 __attribute__((ext_vector_type(4)));
typedef _Float16 f16x8 __attribute__((ext_vector_type(8)));

#define TSEQ 512
#define IDIM 4
#define BPB 16
#define TCH 32              // x staging chunk, in steps
#define GSTR 20             // raw-gate row stride (dwords): 16 data + 4 pad
#define L2E 1.44269504088896340736f

#if __has_builtin(__builtin_amdgcn_exp2f)
#define EX2(v) __builtin_amdgcn_exp2f(v)
#else
#define EX2(v) exp2f(v)
#endif
#define RCP(v) __builtin_amdgcn_rcpf(v)

__global__ __launch_bounds__(256, 2) void lstm_fused(
    const float* __restrict__ x,
    const float* __restrict__ W_ih,
    const float* __restrict__ W_hh,
    const float* __restrict__ b_ih,
    const float* __restrict__ b_hh,
    const float* __restrict__ W_fc,
    const float* __restrict__ b_fc,
    float* __restrict__ out)
{
    __shared__ __align__(16) float    graw[256 * GSTR];   // 20480 B raw gates
    __shared__ __align__(16) _Float16 hbuf[BPB * 64];     // 2048 B, swizzled
    __shared__ __align__(16) float4   xstage[BPB * 33];   // 8448 B, row stride 33

    const int tid  = threadIdx.x;
    const int lane = tid & 63;
    const int wv   = tid >> 6;       // wave id == gate type (0=i,1=f,2=g,3=o)
    const int b0   = blockIdx.x * BPB;
    const int r    = lane & 15;      // B-col (gate) / A-row (batch) lane index
    const int g16  = lane >> 4;      // k-group

    const float swv = (wv == 2) ? 2.0f * L2E : L2E;   // g-gate gets tanh's 2x

    // ---- B-fragments: W^T for this wave's 64 gates, pre-scaled, registers ----
    f16x8 bfrag[4][3];
    float bias[4];
    #pragma unroll
    for (int nt = 0; nt < 4; ++nt) {
        const int g = wv * 64 + nt * 16 + r;
        #pragma unroll
        for (int ks = 0; ks < 2; ++ks) {
            const float* p = W_hh + g * 64 + ks * 32 + g16 * 8;
            f16x8 f;
            #pragma unroll
            for (int j = 0; j < 8; ++j) f[j] = (_Float16)(p[j] * swv);
            bfrag[nt][ks] = f;
        }
        f16x8 f;
        #pragma unroll
        for (int j = 0; j < 8; ++j) f[j] = (_Float16)0.0f;
        if (g16 == 0) {
            #pragma unroll
            for (int j = 0; j < 4; ++j) f[j] = (_Float16)(W_ih[g * IDIM + j] * swv);
        }
        bfrag[nt][2] = f;
        bias[nt] = (b_ih[g] + b_hh[g]) * swv;
    }
    const float wfc = W_fc[lane];
    const float bfc = b_fc[0];

    float c_reg[4] = {0.f, 0.f, 0.f, 0.f};
    float hsave[4] = {0.f, 0.f, 0.f, 0.f};
    for (int i = tid; i < BPB * 64; i += 256) hbuf[i] = (_Float16)0.0f;

    // ---- x chunk-0 prefetch into regs (2 float4/thread) ----
    const int bb0 = tid >> 5, tf = tid & 31;
    const float* xg0 = x + ((size_t)(b0 + bb0)     * TSEQ + tf) * IDIM;
    const float* xg1 = x + ((size_t)(b0 + bb0 + 8) * TSEQ + tf) * IDIM;
    float4 xn0 = *(const float4*)xg0;
    float4 xn1 = *(const float4*)xg1;

    // ---- precomputed LDS addresses ----
    const int hbase = r * 128;
    const int hs0 = ((g16 + 0) << 4) ^ ((r & 7) << 4);
    const int hs1 = ((g16 + 4) << 4) ^ ((r & 7) << 4);
    // phase A store: tile nt -> row (wv*64 + nt*16 + r), col 4*g16 (f32x4)
    float* gst = graw + (wv * 64 + r) * GSTR + 4 * g16;
    // phase B read: type t -> row (t*64 + lane), col 4*wv (f32x4)
    const float* gb = graw + lane * GSTR + 4 * wv;
    int hstb[4];
    #pragma unroll
    for (int q = 0; q < 4; ++q) {
        int bl = 4 * wv + q;
        hstb[q] = (bl * 128 + lane * 2) ^ ((bl & 7) << 4);       // swizzled h store
    }

    for (int tc = 0; tc < TSEQ; tc += TCH) {
        // ---- stage x chunk (regs -> LDS), then issue next chunk's loads ----
        xstage[bb0 * 33 + tf]       = xn0;
        xstage[(bb0 + 8) * 33 + tf] = xn1;
        __syncthreads();
        if (tc + TCH < TSEQ) {
            xn0 = *(const float4*)(xg0 + (tc + TCH) * IDIM);
            xn1 = *(const float4*)(xg1 + (tc + TCH) * IDIM);
        }

        for (int tt = 0; tt < TCH; ++tt) {
            // ================= phase A: MFMA -> raw gates =================
            f16x8 a0 = *(const f16x8*)((const char*)hbuf + hbase + hs0);
            f16x8 a1 = *(const f16x8*)((const char*)hbuf + hbase + hs1);
            float4 xv = xstage[r * 33 + tt];
            const bool isx = (g16 == 0);
            f16x8 ax;
            ax[0] = (_Float16)(isx ? xv.x : 0.f);
            ax[1] = (_Float16)(isx ? xv.y : 0.f);
            ax[2] = (_Float16)(isx ? xv.z : 0.f);
            ax[3] = (_Float16)(isx ? xv.w : 0.f);
            ax[4] = (_Float16)0.f; ax[5] = (_Float16)0.f;
            ax[6] = (_Float16)0.f; ax[7] = (_Float16)0.f;

            f32x4 acc[4];
            __builtin_amdgcn_s_setprio(1);
            #pragma unroll
            for (int nt = 0; nt < 4; ++nt) {
                f32x4 a; a[0] = a[1] = a[2] = a[3] = bias[nt];
                a = __builtin_amdgcn_mfma_f32_16x16x32_f16(a0, bfrag[nt][0], a, 0, 0, 0);
                a = __builtin_amdgcn_mfma_f32_16x16x32_f16(a1, bfrag[nt][1], a, 0, 0, 0);
                a = __builtin_amdgcn_mfma_f32_16x16x32_f16(ax, bfrag[nt][2], a, 0, 0, 0);
                acc[nt] = a;
            }
            __builtin_amdgcn_s_setprio(0);

            // D[row=batch=4*g16+reg][col=hidden=nt*16+r] -> [type][h][batch]:
            // one b128 store per tile at row nt*16+r, cols 4*g16..4*g16+3.
            #pragma unroll
            for (int nt = 0; nt < 4; ++nt)
                *(f32x4*)(gst + nt * 16 * GSTR) = acc[nt];
            __syncthreads();   // raw gates ready

            // ============ phase B: combined activation + state update ============
            f32x4 vI = *(const f32x4*)(gb + 0 * 64 * GSTR);
            f32x4 vF = *(const f32x4*)(gb + 1 * 64 * GSTR);
            f32x4 vG = *(const f32x4*)(gb + 2 * 64 * GSTR);
            f32x4 vO = *(const f32x4*)(gb + 3 * 64 * GSTR);
            #pragma unroll
            for (int q = 0; q < 4; ++q) {
                float ei = EX2(-vI[q]);                 // e^-ai
                float eg = EX2(-vG[q]);                 // e^-2ag
                float ef = EX2(-vF[q]);
                float eo = EX2(-vO[q]);
                float ig = (1.f - eg) * RCP((1.f + ei) * (1.f + eg));  // i*g
                float fg = RCP(1.f + ef);                              // f
                float c  = fg * c_reg[q] + ig;
                c_reg[q] = c;
                float uc = fminf(fmaxf(c * (2.0f * L2E), -60.f), 60.f);
                float et = EX2(-uc);                                   // e^-2c
                float h  = (1.f - et) * RCP((1.f + eo) * (1.f + et));  // o*tanh(c)
                hsave[q] = h;
                *(_Float16*)((char*)hbuf + hstb[q]) = (_Float16)h;
            }
            __syncthreads();   // h ready for next step
        }
    }

    // ---- FC epilogue: out[b] = sum_h h[b][h]*W_fc[h] + b_fc ----
    #pragma unroll
    for (int q = 0; q < 4; ++q) {
        float partial = hsave[q] * wfc;
        #pragma unroll
        for (int off = 32; off > 0; off >>= 1)
            partial += __shfl_down(partial, off);
        if (lane == 0) out[b0 + 4 * wv + q] = partial + bfc;
    }
}

extern "C" void kernel_launch(void* const* d_in, const int* in_sizes, int n_in,
                              void* d_out, int out_size, void* d_ws, size_t ws_size,
                              hipStream_t stream) {
    const float* x    = (const float*)d_in[0];
    const float* W_ih = (const float*)d_in[1];
    const float* W_hh = (const float*)d_in[2];
    const float* b_ih = (const float*)d_in[3];
    const float* b_hh = (const float*)d_in[4];
    const float* W_fc = (const float*)d_in[5];
    const float* b_fc = (const float*)d_in[6];
    float* out = (float*)d_out;

    const int B = in_sizes[0] / (TSEQ * IDIM);   // 8192
    lstm_fused<<<B / BPB, 256, 0, stream>>>(x, W_ih, W_hh, b_ih, b_hh, W_fc, b_fc, out);
}

// Round 4
// 330.226 us; speedup vs baseline: 2.0769x; 1.3336x over previous
//
#include <hip/hip_runtime.h>

// FireLSTM: x[8192,512,4] fp32 -> LSTM(H=64) -> FC(64->1), out[8192] fp32.
//
// 512 blocks x 256 thr (4 waves), block owns 16 batch rows. ONE barrier/step:
// wave wv owns h-columns [16wv,16wv+16) for ALL 4 gate types. Per step it runs
// 12x mfma_f32_16x16x32_f16 (4 types x K=96=[h|x|pad]); D tile t gives gate t
// at cell (batch=4*g16+reg, h=16wv+r) -- all 4 types in the SAME thread regs,
// so activation + c/h update is register-local (no gate LDS exchange).
// h double-buffered in LDS (fp16, XOR-swizzled rows): read buf[t&1], write
// buf[(t+1)&1] -> 1 barrier/step, no WAR hazard. Weights pre-scaled by log2e
// (2*log2e for g): 8 trans/cell (5 exp2 + 3 rcp). x staged per 32 steps into
// LDS as fp16x4 (converted once at stage time); vmcnt drains once per chunk.

typedef float f32x4 __attribute__((ext_vector_type(4)));
typedef _Float16 f16x8 __attribute__((ext_vector_type(8)));
typedef _Float16 f16x4 __attribute__((ext_vector_type(4)));

#define TSEQ 512
#define IDIM 4
#define BPB 16
#define TCH 32              // x staging chunk, in steps
#define L2E 1.44269504088896340736f

#if __has_builtin(__builtin_amdgcn_exp2f)
#define EX2(v) __builtin_amdgcn_exp2f(v)
#else
#define EX2(v) exp2f(v)
#endif
#define RCP(v) __builtin_amdgcn_rcpf(v)

__global__ __launch_bounds__(256, 2) void lstm_fused(
    const float* __restrict__ x,
    const float* __restrict__ W_ih,
    const float* __restrict__ W_hh,
    const float* __restrict__ b_ih,
    const float* __restrict__ b_hh,
    const float* __restrict__ W_fc,
    const float* __restrict__ b_fc,
    float* __restrict__ out)
{
    __shared__ __align__(16) _Float16 hbuf[2][BPB * 64];  // 4 KB, XOR-swizzled
    __shared__ __align__(8)  f16x4    xstage[BPB * 33];   // 4224 B (row stride 33)

    const int tid  = threadIdx.x;
    const int lane = tid & 63;
    const int wv   = tid >> 6;       // wave id == h-column group
    const int b0   = blockIdx.x * BPB;
    const int r    = lane & 15;      // D col (h within group) / A row (batch)
    const int g16  = lane >> 4;      // k-group; D rows 4*g16..4*g16+3 = batches

    // ---- B-fragments: 4 gate types x K=96, pre-scaled by log2e, registers ----
    f16x8 bfrag[4][3];
    float bias[4];
    #pragma unroll
    for (int t4 = 0; t4 < 4; ++t4) {
        const float sc = (t4 == 2) ? 2.0f * L2E : L2E;   // g-gate gets tanh's 2x
        const int g = t4 * 64 + wv * 16 + r;             // gate row (type t4, col r)
        #pragma unroll
        for (int ks = 0; ks < 2; ++ks) {                 // k 0..63: W_hh
            const float* p = W_hh + g * 64 + ks * 32 + g16 * 8;
            f16x8 f;
            #pragma unroll
            for (int j = 0; j < 8; ++j) f[j] = (_Float16)(p[j] * sc);
            bfrag[t4][ks] = f;
        }
        f16x8 f;                                         // k 64..95: W_ih + pad
        #pragma unroll
        for (int j = 0; j < 8; ++j) f[j] = (_Float16)0.0f;
        if (g16 == 0) {
            #pragma unroll
            for (int j = 0; j < 4; ++j) f[j] = (_Float16)(W_ih[g * IDIM + j] * sc);
        }
        bfrag[t4][2] = f;
        bias[t4] = (b_ih[g] + b_hh[g]) * sc;
    }
    const float wfc = W_fc[lane];
    const float bfc = b_fc[0];

    float c_reg[4] = {0.f, 0.f, 0.f, 0.f};
    for (int i = tid; i < BPB * 64; i += 256) hbuf[0][i] = (_Float16)0.0f;

    // ---- x chunk-0 prefetch into regs ----
    const int bb0 = tid >> 5, tf = tid & 31;
    const float* xg0 = x + ((size_t)(b0 + bb0)     * TSEQ + tf) * IDIM;
    const float* xg1 = x + ((size_t)(b0 + bb0 + 8) * TSEQ + tf) * IDIM;
    float4 xn0 = *(const float4*)xg0;
    float4 xn1 = *(const float4*)xg1;

    // ---- precomputed LDS byte offsets (within one parity buffer) ----
    const int hbase = r * 128;                            // A-read row (batch=r)
    const int hs0 = ((g16 + 0) << 4) ^ ((r & 7) << 4);    // k 0..31 chunk
    const int hs1 = ((g16 + 4) << 4) ^ ((r & 7) << 4);    // k 32..63 chunk
    int hw[4];                                            // h scatter-writes
    #pragma unroll
    for (int q = 0; q < 4; ++q) {
        const int bat = 4 * g16 + q;                      // D row = batch
        hw[q] = (bat * 128 + (wv * 16 + r) * 2) ^ ((bat & 7) << 4);
    }
    char* hb0 = (char*)&hbuf[0][0];
    char* hb1 = (char*)&hbuf[1][0];

    auto step = [&](int tt, const char* rb, char* wb) {
        // A-frags: h_{t-1} (batch=r rows), plus x slice (lanes g16==0)
        f16x8 a0 = *(const f16x8*)(rb + hbase + hs0);
        f16x8 a1 = *(const f16x8*)(rb + hbase + hs1);
        f16x4 xv = f16x4{(_Float16)0.f, (_Float16)0.f, (_Float16)0.f, (_Float16)0.f};
        if (g16 == 0) xv = xstage[r * 33 + tt];
        f16x8 ax;
        ax[0] = xv[0]; ax[1] = xv[1]; ax[2] = xv[2]; ax[3] = xv[3];
        ax[4] = (_Float16)0.f; ax[5] = (_Float16)0.f;
        ax[6] = (_Float16)0.f; ax[7] = (_Float16)0.f;

        f32x4 acc[4];
        __builtin_amdgcn_s_setprio(1);
        #pragma unroll
        for (int t4 = 0; t4 < 4; ++t4) {
            f32x4 a; a[0] = a[1] = a[2] = a[3] = bias[t4];
            a = __builtin_amdgcn_mfma_f32_16x16x32_f16(a0, bfrag[t4][0], a, 0, 0, 0);
            a = __builtin_amdgcn_mfma_f32_16x16x32_f16(a1, bfrag[t4][1], a, 0, 0, 0);
            a = __builtin_amdgcn_mfma_f32_16x16x32_f16(ax, bfrag[t4][2], a, 0, 0, 0);
            acc[t4] = a;
        }
        __builtin_amdgcn_s_setprio(0);

        // register-local activations: acc[t][q] all live at cell
        // (batch=4*g16+q, h=16*wv+r). 8 trans/cell: 5 exp2 + 3 rcp.
        #pragma unroll
        for (int q = 0; q < 4; ++q) {
            float ei = EX2(-acc[0][q]);                    // e^-ai
            float ef = EX2(-acc[1][q]);
            float eg = EX2(-acc[2][q]);                    // e^-2ag
            float eo = EX2(-acc[3][q]);
            float ig = (1.f - eg) * RCP((1.f + ei) * (1.f + eg));  // i*g
            float ff = RCP(1.f + ef);                              // f
            float c  = ff * c_reg[q] + ig;
            c_reg[q] = c;
            float uc = fminf(fmaxf(c * (2.0f * L2E), -60.f), 60.f);
            float et = EX2(-uc);                                   // e^-2c
            float h  = (1.f - et) * RCP((1.f + eo) * (1.f + et));  // o*tanh(c)
            *(_Float16*)(wb + hw[q]) = (_Float16)h;
        }
        __syncthreads();   // h_t visible; next step reads wb, writes rb
    };

    for (int tc = 0; tc < TSEQ; tc += TCH) {
        // stage x chunk (fp32 regs -> fp16 LDS), then issue next chunk's loads
        f16x4 s0, s1;
        s0[0] = (_Float16)xn0.x; s0[1] = (_Float16)xn0.y;
        s0[2] = (_Float16)xn0.z; s0[3] = (_Float16)xn0.w;
        s1[0] = (_Float16)xn1.x; s1[1] = (_Float16)xn1.y;
        s1[2] = (_Float16)xn1.z; s1[3] = (_Float16)xn1.w;
        xstage[bb0 * 33 + tf]       = s0;
        xstage[(bb0 + 8) * 33 + tf] = s1;
        __syncthreads();
        if (tc + TCH < TSEQ) {
            xn0 = *(const float4*)(xg0 + (tc + TCH) * IDIM);
            xn1 = *(const float4*)(xg1 + (tc + TCH) * IDIM);
        }
        for (int tt = 0; tt < TCH; tt += 2) {   // parity unrolled: offsets fold
            step(tt,     hb0, hb1);
            step(tt + 1, hb1, hb0);
        }
    }

    // ---- FC epilogue: final h is in hbuf[0] (t=511 wrote parity 0) ----
    #pragma unroll
    for (int q = 0; q < 4; ++q) {
        const int bat = 4 * wv + q;
        const int byte = (bat * 128 + lane * 2) ^ ((bat & 7) << 4);
        float hv = (float)*(const _Float16*)(hb0 + byte);
        float partial = hv * wfc;
        #pragma unroll
        for (int off = 32; off > 0; off >>= 1)
            partial += __shfl_down(partial, off);
        if (lane == 0) out[b0 + bat] = partial + bfc;
    }
}

extern "C" void kernel_launch(void* const* d_in, const int* in_sizes, int n_in,
                              void* d_out, int out_size, void* d_ws, size_t ws_size,
                              hipStream_t stream) {
    const float* x    = (const float*)d_in[0];
    const float* W_ih = (const float*)d_in[1];
    const float* W_hh = (const float*)d_in[2];
    const float* b_ih = (const float*)d_in[3];
    const float* b_hh = (const float*)d_in[4];
    const float* W_fc = (const float*)d_in[5];
    const float* b_fc = (const float*)d_in[6];
    float* out = (float*)d_out;

    const int B = in_sizes[0] / (TSEQ * IDIM);   // 8192
    lstm_fused<<<B / BPB, 256, 0, stream>>>(x, W_ih, W_hh, b_ih, b_hh, W_fc, b_fc, out);
}